// Round 5
// baseline (385.589 us; speedup 1.0000x reference)
//
#include <hip/hip_runtime.h>

// RoPE2D cos/sin table generator — float32.
// Output: [cos_2d (rows*dim)] ++ [sin_2d (rows*dim)], rows = H*W, dim = dimx+dimy.
// Row p = y*W + x. Channel c:
//   c in [0, dimx):   ang = x * ifx[c mod (dimx/2)]
//   c in [dimx, dim): ang = y * ify[(c-dimx) mod (dimy/2)]
// Fast path: one thread = 8 consecutive channels of one row; emits cos AND sin
// (identical angles, sin half at +rows*dim) as 4 nontemporal dwordx4 stores.
// All stores lane-dense (64 lanes x 16 B = 1 KB contiguous per instruction).
// Output is write-once/never-read -> nontemporal to skip L2 write-allocate.

typedef __attribute__((ext_vector_type(4))) float float4v;
typedef __attribute__((ext_vector_type(8))) float float8v;

// dimx = dimy = 64 (dim = 128, half-tables of 32; fidx = ch & 31 in both halves;
// an 8-aligned block of 8 channels never crosses the x/y table boundary).
__global__ __launch_bounds__(256) void rope2d_fast(
    const float* __restrict__ ifx,
    const float* __restrict__ ify,
    const int* __restrict__ wptr,
    float* __restrict__ out,
    int rows)
{
    const int idx = blockIdx.x * blockDim.x + threadIdx.x;
    const int nthr = rows << 4;              // rows*128/8 threads over cos half
    if (idx >= nthr) return;

    const int p  = idx >> 4;                 // row
    const int ch = (idx & 15) << 3;          // first channel (8-aligned)
    const int e  = (idx << 3);               // element offset in cos half
    const int half = rows << 7;              // rows*128 elements

    const int W = *wptr;                     // wave-uniform -> s_load
    int xw, yh;
    if ((W & (W - 1)) == 0) {                // pow2 fast path (W=512)
        const int s = __ffs(W) - 1;
        xw = p & (W - 1);
        yh = p >> s;
    } else {
        xw = p % W;
        yh = p / W;
    }

    const bool use_x = ch < 64;              // [0,64)->x table, [64,128)->y table
    const float pos = use_x ? (float)xw : (float)yh;
    const float* tab = use_x ? ifx : ify;
    const float8v fr = *reinterpret_cast<const float8v*>(tab + (ch & 31));
    // ch&31 in {0,8,16,24}: 8 entries stay within the 32-entry half-table. 32B load.

    float4v c0, c1, s0, s1;
#pragma unroll
    for (int i = 0; i < 4; ++i) {
        const float a0 = pos * fr[i];        // |ang| <= 511 rad, in v_sin range
        const float a1 = pos * fr[i + 4];
        c0[i] = __cosf(a0);  s0[i] = __sinf(a0);
        c1[i] = __cosf(a1);  s1[i] = __sinf(a1);
    }

    float4v* pc = reinterpret_cast<float4v*>(out + e);
    float4v* ps = reinterpret_cast<float4v*>(out + half + e);
    __builtin_nontemporal_store(c0, pc);
    __builtin_nontemporal_store(c1, pc + 1);
    __builtin_nontemporal_store(s0, ps);
    __builtin_nontemporal_store(s1, ps + 1);
}

// Generic path: arbitrary dimx/dimy (scalar per element pair).
__global__ __launch_bounds__(256) void rope2d_generic(
    const float* __restrict__ ifx,
    const float* __restrict__ ify,
    const int* __restrict__ wptr,
    float* __restrict__ out,
    int rows, int dimx, int dimy)
{
    const int dim = dimx + dimy;
    const long long halfo = (long long)rows * dim;
    const long long e = (long long)(blockIdx.x * blockDim.x + threadIdx.x);
    if (e >= halfo) return;

    const int p  = (int)(e / dim);
    const int ch = (int)(e % dim);

    const int W = *wptr;
    const int xw = p % W, yh = p / W;

    float pos, f;
    if (ch < dimx) { pos = (float)xw; f = ifx[ch % (dimx >> 1)]; }
    else           { pos = (float)yh; f = ify[(ch - dimx) % (dimy >> 1)]; }
    const float ang = pos * f;
    out[e]         = __cosf(ang);
    out[halfo + e] = __sinf(ang);
}

extern "C" void kernel_launch(void* const* d_in, const int* in_sizes, int n_in,
                              void* d_out, int out_size, void* d_ws, size_t ws_size,
                              hipStream_t stream) {
    // inputs: [0]=x (f32, dtype-only), [1]=inv_freq_x (f32), [2]=inv_freq_y (f32),
    //         [3]=height (int32), [4]=width (int32)
    const float* ifx = (const float*)d_in[1];
    const float* ify = (const float*)d_in[2];
    const int* wptr  = (const int*)d_in[4];
    float* out = (float*)d_out;

    const int dimx = 2 * in_sizes[1];      // 64
    const int dimy = 2 * in_sizes[2];      // 64
    const int dim  = dimx + dimy;          // 128
    const int rows = in_sizes[0] / dim;    // H*W = 262144

    if (dimx == 64 && dimy == 64) {
        const int nthr = rows << 4;                        // 4,194,304 threads
        const int block = 256;
        const int grid = (nthr + block - 1) / block;       // 16,384 blocks
        rope2d_fast<<<grid, block, 0, stream>>>(ifx, ify, wptr, out, rows);
    } else {
        const long long halfo = (long long)rows * dim;
        const int block = 256;
        const int grid = (int)((halfo + block - 1) / block);
        rope2d_generic<<<grid, block, 0, stream>>>(ifx, ify, wptr, out, rows, dimx, dimy);
    }
}

// Round 6
// 329.771 us; speedup vs baseline: 1.1693x; 1.1693x over previous
//
#include <hip/hip_runtime.h>

// RoPE2D cos/sin table generator — float32.
// Output: [cos_2d (rows*dim)] ++ [sin_2d (rows*dim)], rows = H*W, dim = dimx+dimy.
// Row p = y*W + x. Channel c:
//   c in [0, dimx):   ang = x * ifx[c mod (dimx/2)]
//   c in [dimx, dim): ang = y * ify[(c-dimx) mod (dimy/2)]
// Fast path: one thread = 8 consecutive channels of one row; emits cos AND sin
// (identical angles, sin half at +rows*dim) as 4 plain dwordx4 stores.
// All stores lane-dense (64 lanes x 16 B = 1 KB contiguous per instruction).
// NOTE (R5 post-mortem): __builtin_nontemporal_store regressed +57 us here —
// on gfx950 the L2 write-back path is faster for streaming writes. Keep plain.

typedef __attribute__((ext_vector_type(4))) float float4v;
typedef __attribute__((ext_vector_type(8))) float float8v;

// dimx = dimy = 64 (dim = 128, half-tables of 32; fidx = ch & 31 in both halves;
// an 8-aligned block of 8 channels never crosses the x/y table boundary).
__global__ __launch_bounds__(256) void rope2d_fast(
    const float* __restrict__ ifx,
    const float* __restrict__ ify,
    const int* __restrict__ wptr,
    float* __restrict__ out,
    int rows)
{
    const int idx = blockIdx.x * blockDim.x + threadIdx.x;
    const int nthr = rows << 4;              // rows*128/8 threads over cos half
    if (idx >= nthr) return;

    const int p  = idx >> 4;                 // row
    const int ch = (idx & 15) << 3;          // first channel (8-aligned)
    const int e  = (idx << 3);               // element offset in cos half
    const int half = rows << 7;              // rows*128 elements

    const int W = *wptr;                     // wave-uniform -> s_load
    int xw, yh;
    if ((W & (W - 1)) == 0) {                // pow2 fast path (W=512)
        const int s = __ffs(W) - 1;
        xw = p & (W - 1);
        yh = p >> s;
    } else {
        xw = p % W;
        yh = p / W;
    }

    const bool use_x = ch < 64;              // [0,64)->x table, [64,128)->y table
    const float pos = use_x ? (float)xw : (float)yh;
    const float* tab = use_x ? ifx : ify;
    const float8v fr = *reinterpret_cast<const float8v*>(tab + (ch & 31));
    // ch&31 in {0,8,16,24}: 8 entries stay within the 32-entry half-table. 32B load.

    float4v c0, c1, s0, s1;
#pragma unroll
    for (int i = 0; i < 4; ++i) {
        const float a0 = pos * fr[i];        // |ang| <= 511 rad, in v_sin range
        const float a1 = pos * fr[i + 4];
        c0[i] = __cosf(a0);  s0[i] = __sinf(a0);
        c1[i] = __cosf(a1);  s1[i] = __sinf(a1);
    }

    float4v* pc = reinterpret_cast<float4v*>(out + e);
    float4v* ps = reinterpret_cast<float4v*>(out + half + e);
    pc[0] = c0;
    pc[1] = c1;
    ps[0] = s0;
    ps[1] = s1;
}

// Generic path: arbitrary dimx/dimy (scalar per element pair).
__global__ __launch_bounds__(256) void rope2d_generic(
    const float* __restrict__ ifx,
    const float* __restrict__ ify,
    const int* __restrict__ wptr,
    float* __restrict__ out,
    int rows, int dimx, int dimy)
{
    const int dim = dimx + dimy;
    const long long halfo = (long long)rows * dim;
    const long long e = (long long)(blockIdx.x * blockDim.x + threadIdx.x);
    if (e >= halfo) return;

    const int p  = (int)(e / dim);
    const int ch = (int)(e % dim);

    const int W = *wptr;
    const int xw = p % W, yh = p / W;

    float pos, f;
    if (ch < dimx) { pos = (float)xw; f = ifx[ch % (dimx >> 1)]; }
    else           { pos = (float)yh; f = ify[(ch - dimx) % (dimy >> 1)]; }
    const float ang = pos * f;
    out[e]         = __cosf(ang);
    out[halfo + e] = __sinf(ang);
}

extern "C" void kernel_launch(void* const* d_in, const int* in_sizes, int n_in,
                              void* d_out, int out_size, void* d_ws, size_t ws_size,
                              hipStream_t stream) {
    // inputs: [0]=x (f32, dtype-only), [1]=inv_freq_x (f32), [2]=inv_freq_y (f32),
    //         [3]=height (int32), [4]=width (int32)
    const float* ifx = (const float*)d_in[1];
    const float* ify = (const float*)d_in[2];
    const int* wptr  = (const int*)d_in[4];
    float* out = (float*)d_out;

    const int dimx = 2 * in_sizes[1];      // 64
    const int dimy = 2 * in_sizes[2];      // 64
    const int dim  = dimx + dimy;          // 128
    const int rows = in_sizes[0] / dim;    // H*W = 262144

    if (dimx == 64 && dimy == 64) {
        const int nthr = rows << 4;                        // 4,194,304 threads
        const int block = 256;
        const int grid = (nthr + block - 1) / block;       // 16,384 blocks
        rope2d_fast<<<grid, block, 0, stream>>>(ifx, ify, wptr, out, rows);
    } else {
        const long long halfo = (long long)rows * dim;
        const int block = 256;
        const int grid = (int)((halfo + block - 1) / block);
        rope2d_generic<<<grid, block, 0, stream>>>(ifx, ify, wptr, out, rows, dimx, dimy);
    }
}